// Round 1
// baseline (1520.386 us; speedup 1.0000x reference)
//
#include <hip/hip_runtime.h>

#define N_NODES 50000
#define N_EDGES 800000
#define BN_EPS 1e-5f

// ---------------------------------------------------------------------------
// zero a float buffer
__global__ void zero_kernel(float* __restrict__ p, int n) {
    int i = blockIdx.x * blockDim.x + threadIdx.x;
    int stride = gridDim.x * blockDim.x;
    for (; i < n; i += stride) p[i] = 0.f;
}

// ---------------------------------------------------------------------------
// input embedding: h[n][o] = relu(sum_k x[n][k] * W[k][o] + b[o]),  K=5, O=32
__global__ void emb_kernel(const float* __restrict__ x, const float* __restrict__ W,
                           const float* __restrict__ b, float* __restrict__ out) {
    int idx = blockIdx.x * blockDim.x + threadIdx.x;
    if (idx >= N_NODES * 32) return;
    int n = idx >> 5;
    int o = idx & 31;
    const float* xr = x + n * 5;
    float acc = b[o];
#pragma unroll
    for (int k = 0; k < 5; ++k) acc += xr[k] * W[k * 32 + o];
    out[idx] = fmaxf(acc, 0.f);
}

// ---------------------------------------------------------------------------
// per-feature sum and sum-of-squares over N_NODES rows.  stats[0..D)=sum,
// stats[D..2D)=sumsq.  D is a power of two (32/64/128).  Must be zeroed first.
__global__ void stats_kernel(const float* __restrict__ h, float* __restrict__ stats, int D) {
    extern __shared__ float lds[]; // 2*D floats
    int tid = threadIdx.x;
    for (int i = tid; i < 2 * D; i += blockDim.x) lds[i] = 0.f;
    __syncthreads();

    int gtid = blockIdx.x * blockDim.x + tid;
    int f = gtid & (D - 1);
    int row = gtid / D;
    int rstride = (gridDim.x * blockDim.x) / D;
    float s = 0.f, ss = 0.f;
    for (; row < N_NODES; row += rstride) {
        float v = h[row * D + f];
        s += v;
        ss += v * v;
    }
    atomicAdd(&lds[f], s);
    atomicAdd(&lds[D + f], ss);
    __syncthreads();
    for (int i = tid; i < 2 * D; i += blockDim.x) atomicAdd(&stats[i], lds[i]);
}

// ---------------------------------------------------------------------------
// in-place batchnorm (+ optional relu)
__global__ void bn_kernel(float* __restrict__ h, const float* __restrict__ g,
                          const float* __restrict__ beta, const float* __restrict__ stats,
                          int D, int relu) {
    int total = N_NODES * D;
    int idx = blockIdx.x * blockDim.x + threadIdx.x;
    int stride = gridDim.x * blockDim.x;
    const float invN = 1.f / (float)N_NODES;
    for (; idx < total; idx += stride) {
        int f = idx & (D - 1);
        float m = stats[f] * invN;
        float v = stats[D + f] * invN - m * m;
        float y = (h[idx] - m) * rsqrtf(v + BN_EPS) * g[f] + beta[f];
        if (relu) y = fmaxf(y, 0.f);
        h[idx] = y;
    }
}

// ---------------------------------------------------------------------------
// agg[dst[e]][f] += h[src[e]][f]   for all e, f.  D = 1<<logD.
__global__ void scatter_kernel(const float* __restrict__ h, const int* __restrict__ src,
                               const int* __restrict__ dst, float* __restrict__ agg,
                               int logD) {
    const int D = 1 << logD;
    long total = (long)N_EDGES << logD;
    long idx = (long)blockIdx.x * blockDim.x + threadIdx.x;
    long stride = (long)gridDim.x * blockDim.x;
    for (; idx < total; idx += stride) {
        int e = (int)(idx >> logD);
        int f = (int)idx & (D - 1);
        atomicAdd(&agg[(long)dst[e] * D + f], h[(long)src[e] * D + f]);
    }
}

// ---------------------------------------------------------------------------
// out[n][o] = brel[o] + sum_k agg[n][k]*Wrel[k][o] + sum_k h[n][k]*Wroot[k][o]
__global__ void gconv_kernel(const float* __restrict__ h, const float* __restrict__ agg,
                             const float* __restrict__ Wrel, const float* __restrict__ brel,
                             const float* __restrict__ Wroot, float* __restrict__ out,
                             int din, int logDout) {
    const int dout = 1 << logDout;
    int idx = blockIdx.x * blockDim.x + threadIdx.x;
    if (idx >= N_NODES * dout) return;
    int n = idx >> logDout;
    int o = idx & (dout - 1);
    const float* hr = h + (long)n * din;
    const float* ar = agg + (long)n * din;
    float acc = brel[o];
    for (int k = 0; k < din; ++k)
        acc += ar[k] * Wrel[k * dout + o] + hr[k] * Wroot[k * dout + o];
    out[idx] = acc;
}

// ---------------------------------------------------------------------------
// output MLP: relu(h@W1+b1) @ W2 + b2 ; 32 -> 16 -> 2
__global__ void outmlp_kernel(const float* __restrict__ h, const float* __restrict__ W1,
                              const float* __restrict__ b1, const float* __restrict__ W2,
                              const float* __restrict__ b2, float* __restrict__ out) {
    int n = blockIdx.x * blockDim.x + threadIdx.x;
    if (n >= N_NODES) return;
    const float* hr = h + n * 32;
    float hid[16];
#pragma unroll
    for (int j = 0; j < 16; ++j) {
        float a = b1[j];
#pragma unroll
        for (int k = 0; k < 32; ++k) a += hr[k] * W1[k * 16 + j];
        hid[j] = fmaxf(a, 0.f);
    }
#pragma unroll
    for (int o = 0; o < 2; ++o) {
        float a = b2[o];
#pragma unroll
        for (int k = 0; k < 16; ++k) a += hid[k] * W2[k * 2 + o];
        out[n * 2 + o] = a;
    }
}

// ---------------------------------------------------------------------------
extern "C" void kernel_launch(void* const* d_in, const int* in_sizes, int n_in,
                              void* d_out, int out_size, void* d_ws, size_t ws_size,
                              hipStream_t stream) {
    const float* x        = (const float*)d_in[0];
    const int*   ei       = (const int*)d_in[1];
    const int*   src      = ei;
    const int*   dst      = ei + N_EDGES;
    const float* emb_W    = (const float*)d_in[2];
    const float* emb_b    = (const float*)d_in[3];
    const float* emb_g    = (const float*)d_in[4];
    const float* emb_beta = (const float*)d_in[5];
    const float* out_W1   = (const float*)d_in[26];
    const float* out_b1   = (const float*)d_in[27];
    const float* out_W2   = (const float*)d_in[28];
    const float* out_b2   = (const float*)d_in[29];

    float* ws = (float*)d_ws;
    const size_t HMAX = (size_t)N_NODES * 128;
    float* hA    = ws;
    float* hB    = ws + HMAX;
    float* agg   = ws + 2 * HMAX;
    float* stats = ws + 3 * HMAX;

    const int BS = 256;

    // ---- input embedding: Linear(5,32) + ReLU ----
    emb_kernel<<<(N_NODES * 32 + BS - 1) / BS, BS, 0, stream>>>(x, emb_W, emb_b, hA);
    // ---- BN(32), no relu (relu already applied before BN in embedding) ----
    zero_kernel<<<1, BS, 0, stream>>>(stats, 2 * 32);
    stats_kernel<<<512, BS, 2 * 32 * sizeof(float), stream>>>(hA, stats, 32);
    bn_kernel<<<(N_NODES * 32 + BS - 1) / BS, BS, 0, stream>>>(hA, emb_g, emb_beta, stats, 32, 0);

    const int dims[5] = {32, 64, 128, 64, 32};
    float* cur = hA;
    float* nxt = hB;
    for (int i = 0; i < 4; ++i) {
        int din = dims[i], dout = dims[i + 1];
        int logDin = (din == 32) ? 5 : (din == 64) ? 6 : 7;
        int logDout = (dout == 32) ? 5 : (dout == 64) ? 6 : 7;
        const float* Wrel  = (const float*)d_in[6 + 5 * i];
        const float* brel  = (const float*)d_in[7 + 5 * i];
        const float* Wroot = (const float*)d_in[8 + 5 * i];
        const float* g     = (const float*)d_in[9 + 5 * i];
        const float* beta  = (const float*)d_in[10 + 5 * i];

        // agg = segment_sum(h[src], dst)
        zero_kernel<<<(N_NODES * din + BS - 1) / BS, BS, 0, stream>>>(agg, N_NODES * din);
        scatter_kernel<<<4096, BS, 0, stream>>>(cur, src, dst, agg, logDin);
        // h_next = agg @ Wrel + brel + h @ Wroot
        gconv_kernel<<<(N_NODES * dout + BS - 1) / BS, BS, 0, stream>>>(
            cur, agg, Wrel, brel, Wroot, nxt, din, logDout);
        // BN + ReLU
        zero_kernel<<<1, BS, 0, stream>>>(stats, 2 * dout);
        stats_kernel<<<512, BS, 2 * dout * sizeof(float), stream>>>(nxt, stats, dout);
        bn_kernel<<<(N_NODES * dout + BS - 1) / BS, BS, 0, stream>>>(nxt, g, beta, stats, dout, 1);

        float* t = cur; cur = nxt; nxt = t;
    }

    // ---- output MLP ----
    outmlp_kernel<<<(N_NODES + BS - 1) / BS, BS, 0, stream>>>(
        cur, out_W1, out_b1, out_W2, out_b2, (float*)d_out);
}

// Round 2
// 1044.965 us; speedup vs baseline: 1.4550x; 1.4550x over previous
//
#include <hip/hip_runtime.h>

#define N_NODES 50000
#define N_EDGES 800000
#define BN_EPS 1e-5f

// ---------------------------------------------------------------------------
__global__ void zero_f(float* __restrict__ p, int n) {
    int i = blockIdx.x * blockDim.x + threadIdx.x;
    int stride = gridDim.x * blockDim.x;
    for (; i < n; i += stride) p[i] = 0.f;
}
__global__ void zero_i(int* __restrict__ p, int n) {
    int i = blockIdx.x * blockDim.x + threadIdx.x;
    int stride = gridDim.x * blockDim.x;
    for (; i < n; i += stride) p[i] = 0;
}

// ---------------------------------------------------------------------------
// CSR build: histogram of dst
__global__ void hist_kernel(const int* __restrict__ dst, int* __restrict__ cnt) {
    int i = blockIdx.x * blockDim.x + threadIdx.x;
    int stride = gridDim.x * blockDim.x;
    for (; i < N_EDGES; i += stride) atomicAdd(&cnt[dst[i]], 1);
}

// two-level exclusive scan over 50000 counts (196 blocks x 256)
__global__ void scan1_kernel(const int* __restrict__ cnt, int* __restrict__ rp,
                             int* __restrict__ bsum) {
    __shared__ int s[256];
    int t = threadIdx.x;
    int idx = blockIdx.x * 256 + t;
    int v = (idx < N_NODES) ? cnt[idx] : 0;
    s[t] = v;
    __syncthreads();
    for (int off = 1; off < 256; off <<= 1) {
        int x = 0;
        if (t >= off) x = s[t - off];
        __syncthreads();
        s[t] += x;
        __syncthreads();
    }
    if (idx < N_NODES) rp[idx] = s[t] - v;  // local exclusive
    if (t == 255) bsum[blockIdx.x] = s[255];
}
__global__ void scan2_kernel(int* __restrict__ bsum, int nb) {
    __shared__ int s[256];
    int t = threadIdx.x;
    int v = (t < nb) ? bsum[t] : 0;
    s[t] = v;
    __syncthreads();
    for (int off = 1; off < 256; off <<= 1) {
        int x = 0;
        if (t >= off) x = s[t - off];
        __syncthreads();
        s[t] += x;
        __syncthreads();
    }
    if (t < nb) bsum[t] = s[t] - v;  // exclusive block offsets
}
__global__ void scan3_kernel(int* __restrict__ rp, const int* __restrict__ bsum) {
    int idx = blockIdx.x * 256 + threadIdx.x;
    if (idx < N_NODES) rp[idx] += bsum[blockIdx.x];
    if (idx == 0) rp[N_NODES] = N_EDGES;
}

// fill sorted_src: position = rp[dst] + cursor
__global__ void fill_kernel(const int* __restrict__ src, const int* __restrict__ dst,
                            const int* __restrict__ rp, int* __restrict__ cur,
                            int* __restrict__ ssrc) {
    int i = blockIdx.x * blockDim.x + threadIdx.x;
    int stride = gridDim.x * blockDim.x;
    for (; i < N_EDGES; i += stride) {
        int d = dst[i];
        int p = rp[d] + atomicAdd(&cur[d], 1);
        ssrc[p] = src[i];
    }
}

// ---------------------------------------------------------------------------
// agg[n][f] = sum over CSR row of h[ssrc[e]][f]
template <int LOGD>
__global__ void gather_agg_kernel(const float* __restrict__ h, const int* __restrict__ rp,
                                  const int* __restrict__ ssrc, float* __restrict__ agg) {
    const int D = 1 << LOGD;
    int tid = blockIdx.x * blockDim.x + threadIdx.x;
    int node = tid >> LOGD;
    if (node >= N_NODES) return;
    int f = tid & (D - 1);
    int e0 = rp[node], e1 = rp[node + 1];
    float acc = 0.f;
    for (int e = e0; e < e1; ++e) acc += h[((long)ssrc[e] << LOGD) + f];
    agg[tid] = acc;
}

// out[n][f] += sum over CSR row of P[ssrc[e]][f]   (out preloaded with Q)
template <int LOGD>
__global__ void gather_add_kernel(const float* __restrict__ P, const int* __restrict__ rp,
                                  const int* __restrict__ ssrc, float* __restrict__ out) {
    const int D = 1 << LOGD;
    int tid = blockIdx.x * blockDim.x + threadIdx.x;
    int node = tid >> LOGD;
    if (node >= N_NODES) return;
    int f = tid & (D - 1);
    int e0 = rp[node], e1 = rp[node + 1];
    float acc = out[tid];
    for (int e = e0; e < e1; ++e) acc += P[((long)ssrc[e] << LOGD) + f];
    out[tid] = acc;
}

// ---------------------------------------------------------------------------
// input embedding: h[n][o] = relu(sum_k x[n][k] * W[k][o] + b[o]),  K=5, O=32
__global__ void emb_kernel(const float* __restrict__ x, const float* __restrict__ W,
                           const float* __restrict__ b, float* __restrict__ out) {
    int idx = blockIdx.x * blockDim.x + threadIdx.x;
    if (idx >= N_NODES * 32) return;
    int n = idx >> 5;
    int o = idx & 31;
    const float* xr = x + n * 5;
    float acc = b[o];
#pragma unroll
    for (int k = 0; k < 5; ++k) acc += xr[k] * W[k * 32 + o];
    out[idx] = fmaxf(acc, 0.f);
}

// ---------------------------------------------------------------------------
// per-feature sum & sumsq
__global__ void stats_kernel(const float* __restrict__ h, float* __restrict__ stats, int D) {
    extern __shared__ float lds[];  // 2*D floats
    int tid = threadIdx.x;
    for (int i = tid; i < 2 * D; i += blockDim.x) lds[i] = 0.f;
    __syncthreads();
    int gtid = blockIdx.x * blockDim.x + tid;
    int f = gtid & (D - 1);
    int row = gtid / D;
    int rstride = (gridDim.x * blockDim.x) / D;
    float s = 0.f, ss = 0.f;
    for (; row < N_NODES; row += rstride) {
        float v = h[row * D + f];
        s += v;
        ss += v * v;
    }
    atomicAdd(&lds[f], s);
    atomicAdd(&lds[D + f], ss);
    __syncthreads();
    for (int i = tid; i < 2 * D; i += blockDim.x) atomicAdd(&stats[i], lds[i]);
}

// in-place batchnorm (+ optional relu)
__global__ void bn_kernel(float* __restrict__ h, const float* __restrict__ g,
                          const float* __restrict__ beta, const float* __restrict__ stats,
                          int D, int relu) {
    int total = N_NODES * D;
    int idx = blockIdx.x * blockDim.x + threadIdx.x;
    int stride = gridDim.x * blockDim.x;
    const float invN = 1.f / (float)N_NODES;
    for (; idx < total; idx += stride) {
        int f = idx & (D - 1);
        float m = stats[f] * invN;
        float v = stats[D + f] * invN - m * m;
        float y = (h[idx] - m) * rsqrtf(v + BN_EPS) * g[f] + beta[f];
        if (relu) y = fmaxf(y, 0.f);
        h[idx] = y;
    }
}

// ---------------------------------------------------------------------------
// out[n][o] = brel[o] + sum_k agg[n][k]*Wrel[k][o] + sum_k h[n][k]*Wroot[k][o]
__global__ void gconv_kernel(const float* __restrict__ h, const float* __restrict__ agg,
                             const float* __restrict__ Wrel, const float* __restrict__ brel,
                             const float* __restrict__ Wroot, float* __restrict__ out,
                             int din, int logDout) {
    const int dout = 1 << logDout;
    int idx = blockIdx.x * blockDim.x + threadIdx.x;
    if (idx >= N_NODES * dout) return;
    int n = idx >> logDout;
    int o = idx & (dout - 1);
    const float* hr = h + (long)n * din;
    const float* ar = agg + (long)n * din;
    float acc = brel[o];
    for (int k = 0; k < din; ++k)
        acc += ar[k] * Wrel[k * dout + o] + hr[k] * Wroot[k * dout + o];
    out[idx] = acc;
}

// P = h@Wrel ; Q = h@Wroot + brel
__global__ void prem_kernel(const float* __restrict__ h, const float* __restrict__ Wrel,
                            const float* __restrict__ brel, const float* __restrict__ Wroot,
                            float* __restrict__ P, float* __restrict__ Q,
                            int din, int logDout) {
    const int dout = 1 << logDout;
    int idx = blockIdx.x * blockDim.x + threadIdx.x;
    if (idx >= N_NODES * dout) return;
    int n = idx >> logDout;
    int o = idx & (dout - 1);
    const float* hr = h + (long)n * din;
    float p = 0.f, q = brel[o];
    for (int k = 0; k < din; ++k) {
        float hv = hr[k];
        p += hv * Wrel[k * dout + o];
        q += hv * Wroot[k * dout + o];
    }
    P[idx] = p;
    Q[idx] = q;
}

// ---------------------------------------------------------------------------
// output MLP: relu(h@W1+b1) @ W2 + b2 ; 32 -> 16 -> 2
__global__ void outmlp_kernel(const float* __restrict__ h, const float* __restrict__ W1,
                              const float* __restrict__ b1, const float* __restrict__ W2,
                              const float* __restrict__ b2, float* __restrict__ out) {
    int n = blockIdx.x * blockDim.x + threadIdx.x;
    if (n >= N_NODES) return;
    const float* hr = h + n * 32;
    float hid[16];
#pragma unroll
    for (int j = 0; j < 16; ++j) {
        float a = b1[j];
#pragma unroll
        for (int k = 0; k < 32; ++k) a += hr[k] * W1[k * 16 + j];
        hid[j] = fmaxf(a, 0.f);
    }
#pragma unroll
    for (int o = 0; o < 2; ++o) {
        float a = b2[o];
#pragma unroll
        for (int k = 0; k < 16; ++k) a += hid[k] * W2[k * 2 + o];
        out[n * 2 + o] = a;
    }
}

// ---------------------------------------------------------------------------
extern "C" void kernel_launch(void* const* d_in, const int* in_sizes, int n_in,
                              void* d_out, int out_size, void* d_ws, size_t ws_size,
                              hipStream_t stream) {
    const float* x        = (const float*)d_in[0];
    const int*   ei       = (const int*)d_in[1];
    const int*   src      = ei;
    const int*   dst      = ei + N_EDGES;
    const float* emb_W    = (const float*)d_in[2];
    const float* emb_b    = (const float*)d_in[3];
    const float* emb_g    = (const float*)d_in[4];
    const float* emb_beta = (const float*)d_in[5];
    const float* out_W1   = (const float*)d_in[26];
    const float* out_b1   = (const float*)d_in[27];
    const float* out_W2   = (const float*)d_in[28];
    const float* out_b2   = (const float*)d_in[29];

    float* ws = (float*)d_ws;
    const size_t HMAX = (size_t)N_NODES * 128;          // 6.4M floats
    float* hA    = ws;
    float* hB    = ws + HMAX;
    float* P     = ws + 2 * HMAX;                       // max 50000*64 used
    float* stats = ws + 2 * HMAX + (size_t)N_NODES * 64;
    int*   rp    = (int*)(stats + 256);                 // 50001
    int*   cnt   = rp + N_NODES + 1;                    // 50000
    int*   bsum  = cnt + N_NODES;                       // 256
    int*   ssrc  = bsum + 256;                          // 800000

    const int BS = 256;
    const int SCAN_BLOCKS = (N_NODES + 255) / 256;      // 196

    // ---- CSR build (once per call, reused by all 4 layers) ----
    zero_i<<<64, BS, 0, stream>>>(cnt, N_NODES);
    hist_kernel<<<1024, BS, 0, stream>>>(dst, cnt);
    scan1_kernel<<<SCAN_BLOCKS, 256, 0, stream>>>(cnt, rp, bsum);
    scan2_kernel<<<1, 256, 0, stream>>>(bsum, SCAN_BLOCKS);
    scan3_kernel<<<SCAN_BLOCKS, 256, 0, stream>>>(rp, bsum);
    zero_i<<<64, BS, 0, stream>>>(cnt, N_NODES);
    fill_kernel<<<1024, BS, 0, stream>>>(src, dst, rp, cnt, ssrc);

    // ---- input embedding: Linear(5,32) + ReLU, then BN(32) ----
    emb_kernel<<<(N_NODES * 32 + BS - 1) / BS, BS, 0, stream>>>(x, emb_W, emb_b, hA);
    zero_f<<<1, BS, 0, stream>>>(stats, 2 * 32);
    stats_kernel<<<512, BS, 2 * 32 * sizeof(float), stream>>>(hA, stats, 32);
    bn_kernel<<<(N_NODES * 32 + BS - 1) / BS, BS, 0, stream>>>(hA, emb_g, emb_beta, stats, 32, 0);

    // ---- layer 0: din=32 -> dout=64 (gather input side) ----
    {
        const float* Wrel  = (const float*)d_in[6];
        const float* brel  = (const float*)d_in[7];
        const float* Wroot = (const float*)d_in[8];
        const float* g     = (const float*)d_in[9];
        const float* beta  = (const float*)d_in[10];
        gather_agg_kernel<5><<<(N_NODES * 32 + BS - 1) / BS, BS, 0, stream>>>(hA, rp, ssrc, P);
        gconv_kernel<<<(N_NODES * 64 + BS - 1) / BS, BS, 0, stream>>>(hA, P, Wrel, brel, Wroot, hB, 32, 6);
        zero_f<<<1, BS, 0, stream>>>(stats, 2 * 64);
        stats_kernel<<<512, BS, 2 * 64 * sizeof(float), stream>>>(hB, stats, 64);
        bn_kernel<<<(N_NODES * 64 + BS - 1) / BS, BS, 0, stream>>>(hB, g, beta, stats, 64, 1);
    }
    // ---- layer 1: din=64 -> dout=128 (gather input side) ----
    {
        const float* Wrel  = (const float*)d_in[11];
        const float* brel  = (const float*)d_in[12];
        const float* Wroot = (const float*)d_in[13];
        const float* g     = (const float*)d_in[14];
        const float* beta  = (const float*)d_in[15];
        gather_agg_kernel<6><<<(N_NODES * 64 + BS - 1) / BS, BS, 0, stream>>>(hB, rp, ssrc, P);
        gconv_kernel<<<(N_NODES * 128 + BS - 1) / BS, BS, 0, stream>>>(hB, P, Wrel, brel, Wroot, hA, 64, 7);
        zero_f<<<1, BS, 0, stream>>>(stats, 2 * 128);
        stats_kernel<<<512, BS, 2 * 128 * sizeof(float), stream>>>(hA, stats, 128);
        bn_kernel<<<(N_NODES * 128 + BS - 1) / BS, BS, 0, stream>>>(hA, g, beta, stats, 128, 1);
    }
    // ---- layer 2: din=128 -> dout=64 (pre-multiply, gather output side) ----
    {
        const float* Wrel  = (const float*)d_in[16];
        const float* brel  = (const float*)d_in[17];
        const float* Wroot = (const float*)d_in[18];
        const float* g     = (const float*)d_in[19];
        const float* beta  = (const float*)d_in[20];
        prem_kernel<<<(N_NODES * 64 + BS - 1) / BS, BS, 0, stream>>>(hA, Wrel, brel, Wroot, P, hB, 128, 6);
        gather_add_kernel<6><<<(N_NODES * 64 + BS - 1) / BS, BS, 0, stream>>>(P, rp, ssrc, hB);
        zero_f<<<1, BS, 0, stream>>>(stats, 2 * 64);
        stats_kernel<<<512, BS, 2 * 64 * sizeof(float), stream>>>(hB, stats, 64);
        bn_kernel<<<(N_NODES * 64 + BS - 1) / BS, BS, 0, stream>>>(hB, g, beta, stats, 64, 1);
    }
    // ---- layer 3: din=64 -> dout=32 (pre-multiply, gather output side) ----
    {
        const float* Wrel  = (const float*)d_in[21];
        const float* brel  = (const float*)d_in[22];
        const float* Wroot = (const float*)d_in[23];
        const float* g     = (const float*)d_in[24];
        const float* beta  = (const float*)d_in[25];
        prem_kernel<<<(N_NODES * 32 + BS - 1) / BS, BS, 0, stream>>>(hB, Wrel, brel, Wroot, P, hA, 64, 5);
        gather_add_kernel<5><<<(N_NODES * 32 + BS - 1) / BS, BS, 0, stream>>>(P, rp, ssrc, hA);
        zero_f<<<1, BS, 0, stream>>>(stats, 2 * 32);
        stats_kernel<<<512, BS, 2 * 32 * sizeof(float), stream>>>(hA, stats, 32);
        bn_kernel<<<(N_NODES * 32 + BS - 1) / BS, BS, 0, stream>>>(hA, g, beta, stats, 32, 1);
    }

    // ---- output MLP ----
    outmlp_kernel<<<(N_NODES + BS - 1) / BS, BS, 0, stream>>>(
        hA, out_W1, out_b1, out_W2, out_b2, (float*)d_out);
}